// Round 1
// baseline (205.753 us; speedup 1.0000x reference)
//
#include <hip/hip_runtime.h>
#include <cstddef>

#define NCAPS  10
#define BATCH  256
#define NROUTE 1152
#define CIN    8
#define COUT   16
#define T      384          // threads per block (6 waves)
#define RPT    3            // routes per thread: 1152/384
#define NB     2            // batch elements per block
#define NWAVE  (T / 64)
#define NBLK   (NCAPS * (BATCH / NB))   // 1280 blocks

// full-wave scalar sum
__device__ __forceinline__ float wave_sum(float v) {
    v += __shfl_xor(v, 1);  v += __shfl_xor(v, 2);  v += __shfl_xor(v, 4);
    v += __shfl_xor(v, 8);  v += __shfl_xor(v, 16); v += __shfl_xor(v, 32);
    return v;
}

// Component-splitting butterfly: reduces s[0..15] over the 64 lanes.
// On return, lane L (L<16) holds the wave-total of component
// comp(L) = ((L&1)<<3)|((L&2)<<1)|((L&4)>>1)|((L&8)>>3) in s[0].
__device__ __forceinline__ float wave_sum16(float* s, int lane) {
#pragma unroll
    for (int j = 0; j < 8; ++j) {
        float snd = (lane & 1) ? s[j] : s[j + 8];
        float r = __shfl_xor(snd, 1);
        s[j] = ((lane & 1) ? s[j + 8] : s[j]) + r;
    }
#pragma unroll
    for (int j = 0; j < 4; ++j) {
        float snd = (lane & 2) ? s[j] : s[j + 4];
        float r = __shfl_xor(snd, 2);
        s[j] = ((lane & 2) ? s[j + 4] : s[j]) + r;
    }
#pragma unroll
    for (int j = 0; j < 2; ++j) {
        float snd = (lane & 4) ? s[j] : s[j + 2];
        float r = __shfl_xor(snd, 4);
        s[j] = ((lane & 4) ? s[j + 2] : s[j]) + r;
    }
    {
        float snd = (lane & 8) ? s[0] : s[1];
        float r = __shfl_xor(snd, 8);
        s[0] = ((lane & 8) ? s[1] : s[0]) + r;
    }
    s[0] += __shfl_xor(s[0], 16);
    s[0] += __shfl_xor(s[0], 32);
    return s[0];
}

__global__ __launch_bounds__(T, 2) void caps_routing(const float* __restrict__ x,
                                                     const float* __restrict__ W,
                                                     float* __restrict__ out) {
    __shared__ float sred[NWAVE][NB][20];   // [wave][b][comp 0..15, 16=sumE]
    __shared__ float outLDS[NB][COUT];

    const int tid  = threadIdx.x;
    const int lane = tid & 63;
    const int wv   = tid >> 6;

    // XCD-aware swizzle: consecutive-mod-8 blocks (same XCD) get contiguous
    // work -> each XCD touches <=2 capsules, W[c] (590KB) stays in its 4MB L2.
    int g    = blockIdx.x;
    int widx = (g & 7) * (NBLK / 8) + (g >> 3);   // bijective, 1280 % 8 == 0
    int c    = widx >> 7;                          // / (BATCH/NB = 128)
    int b0   = (widx & 127) * NB;

    const float* Wc  = W + (size_t)c * (NROUTE * CIN * COUT);
    const float* xp0 = x + (size_t)b0 * (NROUTE * CIN);
    const float* xp1 = xp0 + NROUTE * CIN;

    // priors in registers: pr[b][k][o], thread owns routes r = tid + k*T
    float pr[NB][RPT][COUT];

    // ---------------- Phase A: priors = x . W ----------------
#pragma unroll
    for (int k = 0; k < RPT; ++k) {
        const int r = tid + k * T;
        const float4* wp  = reinterpret_cast<const float4*>(Wc + (size_t)r * (CIN * COUT));
        const float4* xq0 = reinterpret_cast<const float4*>(xp0 + r * CIN);
        const float4* xq1 = reinterpret_cast<const float4*>(xp1 + r * CIN);
        float4 xa = xq0[0], xb = xq0[1];
        float4 ya = xq1[0], yb = xq1[1];
        float xs0[8] = {xa.x, xa.y, xa.z, xa.w, xb.x, xb.y, xb.z, xb.w};
        float xs1[8] = {ya.x, ya.y, ya.z, ya.w, yb.x, yb.y, yb.z, yb.w};
        float a0[COUT], a1[COUT];
#pragma unroll
        for (int o = 0; o < COUT; ++o) { a0[o] = 0.f; a1[o] = 0.f; }
#pragma unroll
        for (int i = 0; i < CIN; ++i) {
            const float xi = xs0[i];
            const float yi = xs1[i];
#pragma unroll
            for (int j = 0; j < 4; ++j) {
                float4 w4 = wp[i * 4 + j];
                a0[4 * j + 0] = fmaf(xi, w4.x, a0[4 * j + 0]);
                a0[4 * j + 1] = fmaf(xi, w4.y, a0[4 * j + 1]);
                a0[4 * j + 2] = fmaf(xi, w4.z, a0[4 * j + 2]);
                a0[4 * j + 3] = fmaf(xi, w4.w, a0[4 * j + 3]);
                a1[4 * j + 0] = fmaf(yi, w4.x, a1[4 * j + 0]);
                a1[4 * j + 1] = fmaf(yi, w4.y, a1[4 * j + 1]);
                a1[4 * j + 2] = fmaf(yi, w4.z, a1[4 * j + 2]);
                a1[4 * j + 3] = fmaf(yi, w4.w, a1[4 * j + 3]);
            }
        }
#pragma unroll
        for (int o = 0; o < COUT; ++o) { pr[0][k][o] = a0[o]; pr[1][k][o] = a1[o]; }
    }

    // ---------------- Phase B: 3 routing iterations ----------------
    float l[NB][RPT];
#pragma unroll
    for (int b = 0; b < NB; ++b)
#pragma unroll
        for (int k = 0; k < RPT; ++k) l[b][k] = 0.f;

    float og[NB][COUT];   // outputs from previous iteration (valid for it>0)

    const int comp = ((lane & 1) << 3) | ((lane & 2) << 1) | ((lane & 4) >> 1) | ((lane & 8) >> 3);

    for (int it = 0; it < 3; ++it) {
        float s16[NB][COUT];
        float se[NB];
#pragma unroll
        for (int b = 0; b < NB; ++b) {
            se[b] = 0.f;
#pragma unroll
            for (int o = 0; o < COUT; ++o) s16[b][o] = 0.f;
        }

        // fused: logit update (with previous outputs) + exp + weighted-sum partials
#pragma unroll
        for (int b = 0; b < NB; ++b) {
#pragma unroll
            for (int k = 0; k < RPT; ++k) {
                if (it > 0) {
                    float d = 0.f;
#pragma unroll
                    for (int o = 0; o < COUT; ++o) d = fmaf(pr[b][k][o], og[b][o], d);
                    l[b][k] += d;
                }
                const float e = __expf(l[b][k]);   // logits bounded ~|45|, no max-sub needed
                se[b] += e;
#pragma unroll
                for (int o = 0; o < COUT; ++o) s16[b][o] = fmaf(e, pr[b][k][o], s16[b][o]);
            }
        }

        // block reduce: wave butterfly -> LDS -> 32 threads finish + squash
        float sv[NB], sev[NB];
#pragma unroll
        for (int b = 0; b < NB; ++b) {
            sv[b]  = wave_sum16(s16[b], lane);
            sev[b] = wave_sum(se[b]);
        }
        if (lane < 16) {
            sred[wv][0][comp] = sv[0];
            sred[wv][1][comp] = sv[1];
        }
        if (lane == 0) {
            sred[wv][0][16] = sev[0];
            sred[wv][1][16] = sev[1];
        }
        __syncthreads();

        if (tid < 32) {
            const int b = tid >> 4, o = tid & 15;
            float S = 0.f, SE = 0.f;
#pragma unroll
            for (int w2 = 0; w2 < NWAVE; ++w2) {
                S  += sred[w2][b][o];
                SE += sred[w2][b][16];
            }
            const float tt = S / SE;
            float p = tt * tt;
            p += __shfl_xor(p, 1); p += __shfl_xor(p, 2);
            p += __shfl_xor(p, 4); p += __shfl_xor(p, 8);   // p = |s|^2 within 16-lane group
            const float scale = p / ((1.f + p) * sqrtf(p));
            const float val = tt * scale;
            outLDS[b][o] = val;
            if (it == 2) out[((size_t)c * BATCH + b0 + b) * COUT + o] = val;
        }
        __syncthreads();

        if (it < 2) {
#pragma unroll
            for (int b = 0; b < NB; ++b)
#pragma unroll
                for (int o = 0; o < COUT; ++o) og[b][o] = outLDS[b][o];
        }
    }
}

extern "C" void kernel_launch(void* const* d_in, const int* in_sizes, int n_in,
                              void* d_out, int out_size, void* d_ws, size_t ws_size,
                              hipStream_t stream) {
    const float* x = (const float*)d_in[0];
    const float* w = (const float*)d_in[1];
    float* out = (float*)d_out;
    hipLaunchKernelGGL(caps_routing, dim3(NBLK), dim3(T), 0, stream, x, w, out);
}